// Round 2
// baseline (589.223 us; speedup 1.0000x reference)
//
#include <hip/hip_runtime.h>
#include <math.h>

#define BLOCK 256

__device__ __forceinline__ float fast_rcp(float v) {
  float r = __builtin_amdgcn_rcpf(v);
  r = r * (2.0f - v * r);  // 1 Newton step -> ~1 ulp
  return r;
}

// round(clip(v/step, lo, hi)) with exact IEEE division (weights only, once per block)
__device__ __forceinline__ float quant_div(float v, float step, float lo, float hi) {
  float t = v / step;
  t = fminf(fmaxf(t, lo), hi);
  return rintf(t);
}

__global__ __launch_bounds__(BLOCK)
void net_kernel(const float* __restrict__ x,
                const float* __restrict__ alpha_p, const float* __restrict__ beta_p,
                const float* __restrict__ a1p, const float* __restrict__ a2p,
                const float* __restrict__ a3p,
                const float* __restrict__ W1, const float* __restrict__ b1,
                const float* __restrict__ wa1p,
                const float* __restrict__ W2, const float* __restrict__ b2,
                const float* __restrict__ wa2p,
                float* __restrict__ out, int M) {
  // LDS: exactly 40 KiB -> 4 blocks/CU (160 KiB LDS).
  // smw: qW1 transposed [k*16+j], 8 KiB.
  // smx: x chunk, 256 rows x 32 cols, XOR-swizzled smx[row*32 + (col ^ (row&31))], 32 KiB.
  //      After the main loop smx is dead; smx[0..159] is reused for qW2.
  __shared__ __align__(16) float smw[2048];
  __shared__ __align__(16) float smx[8192];

  const int t = threadIdx.x;
  const int row0 = blockIdx.x * BLOCK;
  const int row = row0 + t;

  // Coalesced staging geometry: element e = u*256 + t covers
  //   lrow = u*32 + (t>>3)  (LDS row), cols 4*(t&7)..+3.
  // Per wave-instruction: 8 rows x 128 B contiguous segments -> 16 lines (vs 64 before).
  const int srow = t >> 3;
  const int sc4 = t & 7;

  const float4* __restrict__ x4 = (const float4*)x;

  // Per-u global float4 base index (row-clamped for tail safety; duplicated rows are
  // only consumed by threads with row >= M which never store).
  int gb[8];
#pragma unroll
  for (int u = 0; u < 8; ++u) {
    int gr = row0 + u * 32 + srow;
    gr = gr < M ? gr : (M - 1);
    gb[u] = gr * 32 + sc4;
  }

  // ---- issue chunk-0 prefetch first (deepest latency) ----
  float4 buf[8];
#pragma unroll
  for (int u = 0; u < 8; ++u) buf[u] = x4[(size_t)gb[u]];

  // ---- quantize W1 into LDS (once per block, overlaps with chunk-0 flight) ----
  {
    const float wa1 = wa1p[0];
    for (int e = t; e < 2048; e += BLOCK) {
      int k = e >> 4, j = e & 15;
      smw[e] = quant_div(W1[j * 128 + k], wa1, -128.0f, 127.0f);
    }
  }

  // ---- write chunk 0 into swizzled LDS ----
#pragma unroll
  for (int u = 0; u < 8; ++u) {
    const int b = (u * 32 + srow) * 32;  // lrow*32 ; lrow&31 == srow
    const float* v = (const float*)&buf[u];
#pragma unroll
    for (int i = 0; i < 4; ++i) {
      const int col = 4 * sc4 + i;
      smx[b + (col ^ srow)] = v[i];  // 2-way bank alias per instr -> free
    }
  }
  __syncthreads();

  const float alpha = alpha_p[0], beta = beta_p[0];
  const float a1 = a1p[0], a2 = a2p[0], a3 = a3p[0];
  const float wa1 = wa1p[0], wa2 = wa2p[0];
  const float inv_a1 = 1.0f / a1;  // IEEE once
  const float inv_a2 = 1.0f / a2;
  const float inv_a3 = 1.0f / a3;
  const float scale1 = a1 * wa1;  // h = scale1 * (int dot) + b1   (dot exact in fp32)
  const float scale2 = a3 * wa2;  // out = scale2 * (int dot) + b2

  const float4* __restrict__ wt = (const float4*)smw;
  const float* __restrict__ myx = smx + t * 32;
  const int sw = t & 31;

  float acc[16];
#pragma unroll
  for (int j = 0; j < 16; ++j) acc[j] = 0.0f;

  float w = 1.0f;

#pragma unroll 1
  for (int cc = 0; cc < 4; ++cc) {
    // issue chunk cc+1 global loads before consuming chunk cc (latency hides under FMAs)
    if (cc < 3) {
#pragma unroll
      for (int u = 0; u < 8; ++u) buf[u] = x4[(size_t)gb[u] + (cc + 1) * 8];
    }
    // consume chunk cc: MFL recurrence + qAct1 + fc1 partial dot (x from LDS, conflict-free)
#pragma unroll
    for (int kk = 0; kk < 32; ++kk) {
      const int k = cc * 32 + kk;
      float tq = w * inv_a1;
      tq = fminf(fmaxf(tq, -128.0f), 127.0f);
      const float q = rintf(tq);
      // wave-uniform weight row (64 B) from LDS — broadcast, conflict-free
      const float4 wr0 = wt[k * 4 + 0];
      const float4 wr1 = wt[k * 4 + 1];
      const float4 wr2 = wt[k * 4 + 2];
      const float4 wr3 = wt[k * 4 + 3];
      acc[0]  = fmaf(q, wr0.x, acc[0]);
      acc[1]  = fmaf(q, wr0.y, acc[1]);
      acc[2]  = fmaf(q, wr0.z, acc[2]);
      acc[3]  = fmaf(q, wr0.w, acc[3]);
      acc[4]  = fmaf(q, wr1.x, acc[4]);
      acc[5]  = fmaf(q, wr1.y, acc[5]);
      acc[6]  = fmaf(q, wr1.z, acc[6]);
      acc[7]  = fmaf(q, wr1.w, acc[7]);
      acc[8]  = fmaf(q, wr2.x, acc[8]);
      acc[9]  = fmaf(q, wr2.y, acc[9]);
      acc[10] = fmaf(q, wr2.z, acc[10]);
      acc[11] = fmaf(q, wr2.w, acc[11]);
      acc[12] = fmaf(q, wr3.x, acc[12]);
      acc[13] = fmaf(q, wr3.y, acc[13]);
      acc[14] = fmaf(q, wr3.z, acc[14]);
      acc[15] = fmaf(q, wr3.w, acc[15]);
      // recurrence: w <- w + alpha/w - beta*x[k]   (errors contract: |dw'/dw| < 1)
      const float xk = myx[kk ^ sw];  // 2-way bank alias across wave64 -> free
      const float r = fast_rcp(w);
      w = fmaf(alpha, r, w);
      w = fmaf(-beta, xk, w);
    }
    __syncthreads();  // everyone done reading smx chunk cc
    if (cc < 3) {
#pragma unroll
      for (int u = 0; u < 8; ++u) {
        const int b = (u * 32 + srow) * 32;
        const float* v = (const float*)&buf[u];
#pragma unroll
        for (int i = 0; i < 4; ++i) {
          const int col = 4 * sc4 + i;
          smx[b + (col ^ srow)] = v[i];
        }
      }
      __syncthreads();  // chunk cc+1 visible
    }
  }

  // smx is dead now: reuse smx[0..159] for qW2 (exact IEEE division preserved)
  if (t < 160) smx[t] = quant_div(W2[t], wa2, -128.0f, 127.0f);
  __syncthreads();

  // epilogue: h -> sigmoid -> uq8 -> q8 (all per-lane, register-resident)
  float s3[16];
#pragma unroll
  for (int j = 0; j < 16; ++j) {
    const float h = fmaf(scale1, acc[j], b1[j]);
    const float e = expf(-h);
    const float s = fast_rcp(1.0f + e);
    float t2 = s * inv_a2;
    t2 = fminf(fmaxf(t2, 0.0f), 255.0f);
    const float s2 = rintf(t2) * a2;
    float t3 = s2 * inv_a3;
    t3 = fminf(fmaxf(t3, -128.0f), 127.0f);
    s3[j] = rintf(t3);  // integer-valued float
  }

  // fc2: out[j] = scale2 * sum_i q3[i]*qw2[j][i] + b2[j]  (exact int dot, qW2 from LDS)
  if (row < M) {
    const float4* __restrict__ w2t = (const float4*)smx;
    float* __restrict__ orow = out + (size_t)row * 10;
#pragma unroll
    for (int j = 0; j < 10; ++j) {
      const float4 u0 = w2t[j * 4 + 0];
      const float4 u1 = w2t[j * 4 + 1];
      const float4 u2 = w2t[j * 4 + 2];
      const float4 u3 = w2t[j * 4 + 3];
      float a = s3[0] * u0.x;
      a = fmaf(s3[1],  u0.y, a);
      a = fmaf(s3[2],  u0.z, a);
      a = fmaf(s3[3],  u0.w, a);
      a = fmaf(s3[4],  u1.x, a);
      a = fmaf(s3[5],  u1.y, a);
      a = fmaf(s3[6],  u1.z, a);
      a = fmaf(s3[7],  u1.w, a);
      a = fmaf(s3[8],  u2.x, a);
      a = fmaf(s3[9],  u2.y, a);
      a = fmaf(s3[10], u2.z, a);
      a = fmaf(s3[11], u2.w, a);
      a = fmaf(s3[12], u3.x, a);
      a = fmaf(s3[13], u3.y, a);
      a = fmaf(s3[14], u3.z, a);
      a = fmaf(s3[15], u3.w, a);
      orow[j] = fmaf(scale2, a, b2[j]);
    }
  }
}

extern "C" void kernel_launch(void* const* d_in, const int* in_sizes, int n_in,
                              void* d_out, int out_size, void* d_ws, size_t ws_size,
                              hipStream_t stream) {
  const float* x     = (const float*)d_in[0];
  const float* alpha = (const float*)d_in[1];
  const float* beta  = (const float*)d_in[2];
  const float* a1    = (const float*)d_in[3];
  const float* a2    = (const float*)d_in[4];
  const float* a3    = (const float*)d_in[5];
  const float* W1    = (const float*)d_in[6];
  const float* b1    = (const float*)d_in[7];
  const float* wa1   = (const float*)d_in[8];
  const float* W2    = (const float*)d_in[9];
  const float* b2    = (const float*)d_in[10];
  const float* wa2   = (const float*)d_in[11];
  float* out = (float*)d_out;
  const int M = in_sizes[0] / 128;
  const int grid = (M + BLOCK - 1) / BLOCK;
  net_kernel<<<grid, BLOCK, 0, stream>>>(x, alpha, beta, a1, a2, a3,
                                         W1, b1, wa1, W2, b2, wa2, out, M);
}

// Round 4
// 258.300 us; speedup vs baseline: 2.2812x; 2.2812x over previous
//
#include <hip/hip_runtime.h>
#include <math.h>

#define BLOCK 256
#define WS_W2_F4 512  // float4 index of W2 block inside ws (float offset 2048)

typedef const unsigned int __attribute__((address_space(1))) gu32_t;
typedef unsigned int __attribute__((address_space(3))) lu32_t;

// Async global->LDS, 16 B per lane, no VGPR round-trip (the R2 spill killer avoided).
__device__ __forceinline__ void stage16(const float* g, float* l) {
  __builtin_amdgcn_global_load_lds((gu32_t*)g, (lu32_t*)l, 16, 0, 0);
}

__device__ __forceinline__ float fast_rcp(float v) {
  float r = __builtin_amdgcn_rcpf(v);
  r = r * (2.0f - v * r);  // 1 Newton step -> ~1 ulp
  return r;
}

// round(clip(v/step, lo, hi)) with exact IEEE division (weights only, once)
__device__ __forceinline__ float quant_div(float v, float step, float lo, float hi) {
  float t = v / step;
  t = fminf(fmaxf(t, lo), hi);
  return rintf(t);
}

// Prepass: quantize weights to integer-valued floats in global ws (R0-proven path:
// wave-uniform ws reads compile to s_load -> weights live in SGPRs/K$, zero VGPR cost).
__global__ void prep_kernel(const float* __restrict__ W1, const float* __restrict__ wa1p,
                            const float* __restrict__ W2, const float* __restrict__ wa2p,
                            float* __restrict__ ws) {
  const int t = threadIdx.x;
  const float wa1 = wa1p[0], wa2 = wa2p[0];
  for (int e = t; e < 2048; e += BLOCK) {
    int k = e >> 4, j = e & 15;
    ws[e] = quant_div(W1[j * 128 + k], wa1, -128.0f, 127.0f);
  }
  if (t < 160) {
    ws[2048 + t] = quant_div(W2[t], wa2, -128.0f, 127.0f);
  }
}

// Consume one 32-col chunk from the swizzled LDS tile.
// Read layout: tile word r*32 + 4*j' + i holds global col 4*(j'^(r&7))+i, so
// col-block jc lives at word r*32 + 4*(jc ^ (r&7)). ds_read_b128 across 64 lanes
// spreads over all 32 banks (8 lane-groups x 4-bank quads) -> demand-limited.
__device__ __forceinline__ void consume32(const float* __restrict__ tile, int t,
                                          const float4* __restrict__ wt, int k0,
                                          float& w, float (&acc)[16],
                                          float inv_a1, float alpha, float beta) {
  const int rsw = t & 7;  // == (row&7) for row = t
  float4 xb[8];
#pragma unroll
  for (int jc = 0; jc < 8; ++jc)
    xb[jc] = *(const float4*)&tile[t * 32 + 4 * (jc ^ rsw)];
  const float* xs = (const float*)xb;
#pragma unroll
  for (int kk = 0; kk < 32; ++kk) {
    const int k = k0 + kk;
    // q = round(clip(w/a1, -128, 127))  (integer-valued float)
    float tq = w * inv_a1;
    tq = fminf(fmaxf(tq, -128.0f), 127.0f);
    const float q = rintf(tq);
    // wave-uniform weight row (64 B) from global ws — scalar-load eligible
    const float4 wr0 = wt[k * 4 + 0];
    const float4 wr1 = wt[k * 4 + 1];
    const float4 wr2 = wt[k * 4 + 2];
    const float4 wr3 = wt[k * 4 + 3];
    acc[0]  = fmaf(q, wr0.x, acc[0]);
    acc[1]  = fmaf(q, wr0.y, acc[1]);
    acc[2]  = fmaf(q, wr0.z, acc[2]);
    acc[3]  = fmaf(q, wr0.w, acc[3]);
    acc[4]  = fmaf(q, wr1.x, acc[4]);
    acc[5]  = fmaf(q, wr1.y, acc[5]);
    acc[6]  = fmaf(q, wr1.z, acc[6]);
    acc[7]  = fmaf(q, wr1.w, acc[7]);
    acc[8]  = fmaf(q, wr2.x, acc[8]);
    acc[9]  = fmaf(q, wr2.y, acc[9]);
    acc[10] = fmaf(q, wr2.z, acc[10]);
    acc[11] = fmaf(q, wr2.w, acc[11]);
    acc[12] = fmaf(q, wr3.x, acc[12]);
    acc[13] = fmaf(q, wr3.y, acc[13]);
    acc[14] = fmaf(q, wr3.z, acc[14]);
    acc[15] = fmaf(q, wr3.w, acc[15]);
    // recurrence: w <- w + alpha/w - beta*x[k]   (errors contract: |dw'/dw| < 1)
    const float xk = xs[kk];
    const float r = fast_rcp(w);
    w = fmaf(alpha, r, w);
    w = fmaf(-beta, xk, w);
  }
}

template <bool USE_WS>
__global__ __launch_bounds__(BLOCK)
void net_kernel(const float* __restrict__ x,
                const float* __restrict__ alpha_p, const float* __restrict__ beta_p,
                const float* __restrict__ a1p, const float* __restrict__ a2p,
                const float* __restrict__ a3p,
                const float* __restrict__ W1, const float* __restrict__ b1,
                const float* __restrict__ wa1p,
                const float* __restrict__ W2, const float* __restrict__ b2,
                const float* __restrict__ wa2p,
                const float* __restrict__ ws,
                float* __restrict__ out, int M) {
  // Double-buffered x tile: 2 x 256 rows x 32 cols = 64 KiB -> 2 blocks/CU.
  __shared__ __align__(16) float smx0[8192];
  __shared__ __align__(16) float smx1[8192];

  const int t = threadIdx.x;
  const int row0 = blockIdx.x * BLOCK;
  const int row = row0 + t;

  // Staging geometry: 16B chunk index c16 = u*256 + t  (u = 0..7 issues/thread/chunk)
  //   local row r = c16>>3 = u*32 + (t>>3)   (r&7 == (t>>3)&7, constant over u)
  //   j' = c16&7 = t&7
  // LDS dest (linear, HW: wave-uniform base + lane*16): word (u*256+t)*4.
  // Global src pre-swizzled (m173): col 4*(j' ^ (r&7)) -> linear LDS == swizzled layout.
  // Coalescing: 8 consecutive lanes cover one aligned 128B line; 8 lines/instr (vs 64).
  const int a = t >> 3;
  const int jp = t & 7;
  const int csw = 4 * (jp ^ (a & 7));
  int gb[8];
#pragma unroll
  for (int u = 0; u < 8; ++u) {
    int gr = row0 + u * 32 + a;
    gr = gr < M ? gr : (M - 1);
    gb[u] = gr * 128 + csw;  // float index; per chunk add cc*32
  }

  // ---- issue chunk 0 stage immediately (deepest latency first) ----
#pragma unroll
  for (int u = 0; u < 8; ++u) stage16(x + gb[u], smx0 + (u * 256 + t) * 4);

  const float alpha = alpha_p[0], beta = beta_p[0];
  const float a1 = a1p[0], a2 = a2p[0], a3 = a3p[0];
  const float wa1 = wa1p[0], wa2 = wa2p[0];
  const float inv_a1 = 1.0f / a1;  // IEEE once
  const float inv_a2 = 1.0f / a2;
  const float inv_a3 = 1.0f / a3;
  const float scale1 = a1 * wa1;   // h = scale1 * (int dot) + b1   (dot exact in fp32)
  const float scale2 = a3 * wa2;   // out = scale2 * (int dot) + b2

  const float4* wt;
  if constexpr (USE_WS) {
    wt = (const float4*)ws;
  } else {
    // fallback: per-block quantize into a small LDS copy (correctness path only)
    __shared__ __align__(16) float smw[2208];
    for (int e = t; e < 2048; e += BLOCK) {
      int k = e >> 4, j = e & 15;
      smw[e] = quant_div(W1[j * 128 + k], wa1, -128.0f, 127.0f);
    }
    if (t < 160) smw[2048 + t] = quant_div(W2[t], wa2, -128.0f, 127.0f);
    wt = (const float4*)smw;
  }

  float acc[16];
#pragma unroll
  for (int j = 0; j < 16; ++j) acc[j] = 0.0f;
  float w = 1.0f;

  __syncthreads();  // drains vmcnt -> chunk 0 resident

  // 2-phase pipeline: issue stage(c+1) BEFORE consume(c); __syncthreads' vmcnt(0)
  // drain doubles as the "next buffer ready" wait (stage latency hides under consume).
#pragma unroll
  for (int u = 0; u < 8; ++u) stage16(x + gb[u] + 32, smx1 + (u * 256 + t) * 4);
  consume32(smx0, t, wt, 0, w, acc, inv_a1, alpha, beta);
  __syncthreads();

#pragma unroll
  for (int u = 0; u < 8; ++u) stage16(x + gb[u] + 64, smx0 + (u * 256 + t) * 4);
  consume32(smx1, t, wt, 32, w, acc, inv_a1, alpha, beta);
  __syncthreads();

#pragma unroll
  for (int u = 0; u < 8; ++u) stage16(x + gb[u] + 96, smx1 + (u * 256 + t) * 4);
  consume32(smx0, t, wt, 64, w, acc, inv_a1, alpha, beta);
  __syncthreads();

  consume32(smx1, t, wt, 96, w, acc, inv_a1, alpha, beta);

  if (row >= M) return;  // barriers all done; safe to exit tail threads now

  // epilogue: h -> sigmoid -> uq8 -> q8 (all per-lane, register-resident)
  float s3[16];
#pragma unroll
  for (int j = 0; j < 16; ++j) {
    const float h = fmaf(scale1, acc[j], b1[j]);
    const float e = expf(-h);
    const float s = fast_rcp(1.0f + e);
    float t2 = s * inv_a2;
    t2 = fminf(fmaxf(t2, 0.0f), 255.0f);
    const float s2 = rintf(t2) * a2;
    float t3 = s2 * inv_a3;
    t3 = fminf(fmaxf(t3, -128.0f), 127.0f);
    s3[j] = rintf(t3);  // integer-valued float
  }

  // fc2: out[j] = scale2 * sum_i q3[i]*qw2[j][i] + b2[j]  (exact int dot)
  float* __restrict__ orow = out + (size_t)row * 10;
#pragma unroll
  for (int j = 0; j < 10; ++j) {
    const float4 u0 = wt[WS_W2_F4 + j * 4 + 0];
    const float4 u1 = wt[WS_W2_F4 + j * 4 + 1];
    const float4 u2 = wt[WS_W2_F4 + j * 4 + 2];
    const float4 u3 = wt[WS_W2_F4 + j * 4 + 3];
    float a0 = s3[0] * u0.x;
    a0 = fmaf(s3[1],  u0.y, a0);
    a0 = fmaf(s3[2],  u0.z, a0);
    a0 = fmaf(s3[3],  u0.w, a0);
    a0 = fmaf(s3[4],  u1.x, a0);
    a0 = fmaf(s3[5],  u1.y, a0);
    a0 = fmaf(s3[6],  u1.z, a0);
    a0 = fmaf(s3[7],  u1.w, a0);
    a0 = fmaf(s3[8],  u2.x, a0);
    a0 = fmaf(s3[9],  u2.y, a0);
    a0 = fmaf(s3[10], u2.z, a0);
    a0 = fmaf(s3[11], u2.w, a0);
    a0 = fmaf(s3[12], u3.x, a0);
    a0 = fmaf(s3[13], u3.y, a0);
    a0 = fmaf(s3[14], u3.z, a0);
    a0 = fmaf(s3[15], u3.w, a0);
    orow[j] = fmaf(scale2, a0, b2[j]);
  }
}

extern "C" void kernel_launch(void* const* d_in, const int* in_sizes, int n_in,
                              void* d_out, int out_size, void* d_ws, size_t ws_size,
                              hipStream_t stream) {
  const float* x     = (const float*)d_in[0];
  const float* alpha = (const float*)d_in[1];
  const float* beta  = (const float*)d_in[2];
  const float* a1    = (const float*)d_in[3];
  const float* a2    = (const float*)d_in[4];
  const float* a3    = (const float*)d_in[5];
  const float* W1    = (const float*)d_in[6];
  const float* b1    = (const float*)d_in[7];
  const float* wa1   = (const float*)d_in[8];
  const float* W2    = (const float*)d_in[9];
  const float* b2    = (const float*)d_in[10];
  const float* wa2   = (const float*)d_in[11];
  float* out = (float*)d_out;
  const int M = in_sizes[0] / 128;
  const int grid = (M + BLOCK - 1) / BLOCK;
  if (ws_size >= 2208 * sizeof(float)) {
    float* ws = (float*)d_ws;
    prep_kernel<<<1, BLOCK, 0, stream>>>(W1, wa1, W2, wa2, ws);
    net_kernel<true><<<grid, BLOCK, 0, stream>>>(x, alpha, beta, a1, a2, a3,
                                                 W1, b1, wa1, W2, b2, wa2, ws, out, M);
  } else {
    net_kernel<false><<<grid, BLOCK, 0, stream>>>(x, alpha, beta, a1, a2, a3,
                                                  W1, b1, wa1, W2, b2, wa2, nullptr, out, M);
  }
}

// Round 5
// 224.062 us; speedup vs baseline: 2.6297x; 1.1528x over previous
//
#include <hip/hip_runtime.h>
#include <math.h>

#define BLOCK 256

// ---- int8 4-way dot with int32 accumulate (v_dot4_i32_i8) ----
#if __has_builtin(__builtin_amdgcn_sdot4)
#define SDOT4(a, b, c) __builtin_amdgcn_sdot4((a), (b), (c), false)
#else
__device__ __forceinline__ int sdot4_sw(int a, int b, int c) {
#pragma unroll
  for (int i = 0; i < 4; ++i)
    c += ((a << (24 - 8 * i)) >> 24) * ((b << (24 - 8 * i)) >> 24);
  return c;
}
#define SDOT4(a, b, c) sdot4_sw((a), (b), (c))
#endif

__device__ __forceinline__ float fast_rcp(float v) {
  float r = __builtin_amdgcn_rcpf(v);
  r = r * (2.0f - v * r);  // 1 Newton step -> ~1 ulp
  return r;
}

// round(clip(v/step, lo, hi)) with exact IEEE division (weights only, once)
__device__ __forceinline__ float quant_div(float v, float step, float lo, float hi) {
  float t = v / step;
  t = fminf(fmaxf(t, lo), hi);
  return rintf(t);
}

// Prepass: quantize weights and pack as int8x4 dwords in ws.
// wsi[kq*16 + j]        (kq=0..31, j=0..15): bytes = qW1[j][4kq..4kq+3]   (512 dwords)
// wsi[512 + j*4 + kq]   (j=0..9,  kq=0..3): bytes = qW2[j][4kq..4kq+3]   (40 dwords)
__global__ void prep_kernel(const float* __restrict__ W1, const float* __restrict__ wa1p,
                            const float* __restrict__ W2, const float* __restrict__ wa2p,
                            int* __restrict__ wsi) {
  const int t = threadIdx.x;
  const float wa1 = wa1p[0], wa2 = wa2p[0];
  for (int e = t; e < 512; e += BLOCK) {
    const int kq = e >> 4, j = e & 15;
    unsigned int d = 0;
#pragma unroll
    for (int i = 0; i < 4; ++i) {
      const int q = (int)quant_div(W1[j * 128 + kq * 4 + i], wa1, -128.0f, 127.0f);
      d |= ((unsigned int)(q & 255)) << (8 * i);
    }
    wsi[e] = (int)d;
  }
  if (t < 40) {
    const int j = t >> 2, kq = t & 3;
    unsigned int d = 0;
#pragma unroll
    for (int i = 0; i < 4; ++i) {
      const int q = (int)quant_div(W2[j * 16 + kq * 4 + i], wa2, -128.0f, 127.0f);
      d |= ((unsigned int)(q & 255)) << (8 * i);
    }
    wsi[512 + t] = (int)d;
  }
}

// Consume 32 columns: MFL recurrence + qAct1 + fc1 partial dot (int8 dot4 path).
// Weight row per 4 columns = 16 dwords (64 B) wave-uniform -> one s_load_dwordx16
// (vs 16 s_load_dwordx4 before): 16x fewer scalar loads, 4x fewer fc1 VALU ops.
__device__ __forceinline__ void consume32(const float* __restrict__ xs,
                                          const int* __restrict__ wp, int kq0,
                                          float& w, int (&acc)[16],
                                          float inv_a1, float alpha, float beta) {
#pragma unroll
  for (int kql = 0; kql < 8; ++kql) {
    const int* __restrict__ wrow = wp + (kq0 + kql) * 16;
    unsigned int qpk = 0;
#pragma unroll
    for (int i = 0; i < 4; ++i) {
      // q = round(clip(w/a1, -128, 127)) -> int8, packed into byte i
      float tq = w * inv_a1;
      tq = fminf(fmaxf(tq, -128.0f), 127.0f);
      const int qi = (int)rintf(tq);  // exact: rintf output is integer-valued
      qpk |= ((unsigned int)(qi & 255)) << (8 * i);
      // recurrence: w <- w + alpha/w - beta*x[k]  (same op order as before)
      const float xk = xs[kql * 4 + i];
      const float r = fast_rcp(w);
      w = fmaf(alpha, r, w);
      w = fmaf(-beta, xk, w);
    }
    // |q*w| <= 2^14, 128-term sum <= 2^21: int32 dot == previous fp32 chain bit-exactly
#pragma unroll
    for (int j = 0; j < 16; ++j) acc[j] = SDOT4((int)qpk, wrow[j], acc[j]);
  }
}

__device__ __forceinline__ void load8(float4 (&dst)[8], const float4* __restrict__ src) {
#pragma unroll
  for (int u = 0; u < 8; ++u) dst[u] = src[u];
}

template <bool USE_WS>
__global__ __launch_bounds__(BLOCK, 4)  // cap VGPR at 128 -> 4 waves/SIMD guaranteed
void net_kernel(const float* __restrict__ x,
                const float* __restrict__ alpha_p, const float* __restrict__ beta_p,
                const float* __restrict__ a1p, const float* __restrict__ a2p,
                const float* __restrict__ a3p,
                const float* __restrict__ W1, const float* __restrict__ b1,
                const float* __restrict__ wa1p,
                const float* __restrict__ W2, const float* __restrict__ b2,
                const float* __restrict__ wa2p,
                const int* __restrict__ wsi,
                float* __restrict__ out, int M) {
  const int t = threadIdx.x;
  const float wa1 = wa1p[0], wa2 = wa2p[0];

  const int* wp;
  if constexpr (USE_WS) {
    wp = wsi;
  } else {
    // fallback: per-block pack into LDS (correctness path only)
    __shared__ int smw[552];
    for (int e = t; e < 512; e += BLOCK) {
      const int kq = e >> 4, j = e & 15;
      unsigned int d = 0;
#pragma unroll
      for (int i = 0; i < 4; ++i) {
        const int q = (int)quant_div(W1[j * 128 + kq * 4 + i], wa1, -128.0f, 127.0f);
        d |= ((unsigned int)(q & 255)) << (8 * i);
      }
      smw[e] = (int)d;
    }
    if (t < 40) {
      const int j = t >> 2, kq = t & 3;
      unsigned int d = 0;
#pragma unroll
      for (int i = 0; i < 4; ++i) {
        const int q = (int)quant_div(W2[j * 16 + kq * 4 + i], wa2, -128.0f, 127.0f);
        d |= ((unsigned int)(q & 255)) << (8 * i);
      }
      smw[512 + t] = (int)d;
    }
    __syncthreads();
    wp = smw;
  }

  const int row = blockIdx.x * BLOCK + t;
  if (row >= M) return;  // no barriers below in USE_WS path; safe

  const float alpha = alpha_p[0], beta = beta_p[0];
  const float a1 = a1p[0], a2 = a2p[0], a3 = a3p[0];
  const float inv_a1 = 1.0f / a1;  // IEEE once
  const float inv_a2 = 1.0f / a2;
  const float inv_a3 = 1.0f / a3;
  const float scale1 = a1 * wa1;   // h = scale1 * (int dot) + b1   (dot exact)
  const float scale2 = a3 * wa2;   // out = scale2 * (int dot) + b2

  const float4* __restrict__ xr = (const float4*)(x + (size_t)row * 128);

  int acc[16];
#pragma unroll
  for (int j = 0; j < 16; ++j) acc[j] = 0;
  float w = 1.0f;

  // Register double-buffer: chunk c+1's 8 float4 loads are in flight while chunk c's
  // 32 columns (quant+pack+dot+recurrence) execute -> vmcnt waits land after compute.
  float4 bufA[8], bufB[8];
  load8(bufA, xr + 0);
  load8(bufB, xr + 8);
  consume32((const float*)bufA, wp, 0,  w, acc, inv_a1, alpha, beta);
  load8(bufA, xr + 16);
  consume32((const float*)bufB, wp, 8,  w, acc, inv_a1, alpha, beta);
  load8(bufB, xr + 24);
  consume32((const float*)bufA, wp, 16, w, acc, inv_a1, alpha, beta);
  consume32((const float*)bufB, wp, 24, w, acc, inv_a1, alpha, beta);

  // epilogue: h -> sigmoid -> uq8 -> q8 (per-lane, register-resident)
  int sp[4];
#pragma unroll
  for (int g = 0; g < 4; ++g) {
    unsigned int d = 0;
#pragma unroll
    for (int i = 0; i < 4; ++i) {
      const int j = g * 4 + i;
      const float h = fmaf(scale1, (float)acc[j], b1[j]);
      const float e = expf(-h);
      const float s = fast_rcp(1.0f + e);
      float t2 = s * inv_a2;
      t2 = fminf(fmaxf(t2, 0.0f), 255.0f);
      const float s2 = rintf(t2) * a2;
      float t3 = s2 * inv_a3;
      t3 = fminf(fmaxf(t3, -128.0f), 127.0f);
      const int qi = (int)rintf(t3);
      d |= ((unsigned int)(qi & 255)) << (8 * i);
    }
    sp[g] = (int)d;
  }

  // fc2: out[j] = scale2 * (int8 dot16) + b2[j]  (|sum| <= 16*127^2 < 2^24: exact)
  const int* __restrict__ w2p = wp + 512;
  float* __restrict__ orow = out + (size_t)row * 10;
#pragma unroll
  for (int j = 0; j < 10; ++j) {
    int a0 = 0;
#pragma unroll
    for (int g = 0; g < 4; ++g) a0 = SDOT4(sp[g], w2p[j * 4 + g], a0);
    orow[j] = fmaf(scale2, (float)a0, b2[j]);
  }
}

extern "C" void kernel_launch(void* const* d_in, const int* in_sizes, int n_in,
                              void* d_out, int out_size, void* d_ws, size_t ws_size,
                              hipStream_t stream) {
  const float* x     = (const float*)d_in[0];
  const float* alpha = (const float*)d_in[1];
  const float* beta  = (const float*)d_in[2];
  const float* a1    = (const float*)d_in[3];
  const float* a2    = (const float*)d_in[4];
  const float* a3    = (const float*)d_in[5];
  const float* W1    = (const float*)d_in[6];
  const float* b1    = (const float*)d_in[7];
  const float* wa1   = (const float*)d_in[8];
  const float* W2    = (const float*)d_in[9];
  const float* b2    = (const float*)d_in[10];
  const float* wa2   = (const float*)d_in[11];
  float* out = (float*)d_out;
  const int M = in_sizes[0] / 128;
  const int grid = (M + BLOCK - 1) / BLOCK;
  if (ws_size >= 552 * sizeof(int)) {
    int* wsi = (int*)d_ws;
    prep_kernel<<<1, BLOCK, 0, stream>>>(W1, wa1, W2, wa2, wsi);
    net_kernel<true><<<grid, BLOCK, 0, stream>>>(x, alpha, beta, a1, a2, a3,
                                                 W1, b1, wa1, W2, b2, wa2, wsi, out, M);
  } else {
    net_kernel<false><<<grid, BLOCK, 0, stream>>>(x, alpha, beta, a1, a2, a3,
                                                  W1, b1, wa1, W2, b2, wa2, nullptr, out, M);
  }
}